// Round 1
// baseline (128.298 us; speedup 1.0000x reference)
//
#include <hip/hip_runtime.h>

// LCN: B=512, C=1, H=W=280, K=S=28, F=10, SPAN=100 (10x10), DEC_IN=1000, OUT=10
#define B_TOT   512
#define HW      280
#define KK      28
#define F_N     10
#define SPAN_N  100
#define DEC_IN  1000
#define OUT_N   10

// Kernel 1: locally-connected conv + bias + relu.
// grid = 800 blocks: bid = bg*100 + s  (bg in 0..7 -> 64 batches, s in 0..99 patch loc)
// block = 256 threads = 4 waves; wave kh handles rows kh*7 .. kh*7+6 of the 28x28 patch.
// lane = batch within group -> w index is wave-uniform -> scalar (SGPR) loads for w.
// hidden layout: [d=f*100+s][b]  (coalesced store here, coalesced load in decoder)
__global__ __launch_bounds__(256) void lcn_conv(
    const float* __restrict__ x, const float* __restrict__ cw,
    const float* __restrict__ cb, float* __restrict__ hidden) {
  const int bid  = blockIdx.x;           // 0..799
  const int s    = bid % SPAN_N;         // patch location
  const int bg   = bid / SPAN_N;         // 0..7 batch group
  const int kh   = threadIdx.x >> 6;     // 0..3 K-quarter (7 rows each)
  const int lane = threadIdx.x & 63;
  const int b    = bg * 64 + lane;
  const int hs   = s / 10, ws = s % 10;

  // per-lane x stream: this lane's patch, rows kh*7..kh*7+6
  const float* xp = x + (size_t)b * (HW * HW)
                      + (size_t)(hs * KK + kh * 7) * HW + ws * KK;

  float acc[F_N];
#pragma unroll
  for (int f = 0; f < F_N; ++f) acc[f] = 0.f;

  // force wave-uniform w base into SGPR (kh is threadIdx-derived)
  const int wrow0 = __builtin_amdgcn_readfirstlane(s * (KK * KK) + kh * 7 * KK);

  for (int r = 0; r < 7; ++r) {
    float4 xv[7];
    const float4* rx = reinterpret_cast<const float4*>(xp + r * HW);
#pragma unroll
    for (int c = 0; c < 7; ++c) xv[c] = rx[c];   // 28 floats of this patch row

    const int wrow = wrow0 + r * KK;
#pragma unroll
    for (int f = 0; f < F_N; ++f) {
      const float4* wf =
          reinterpret_cast<const float4*>(cw + (size_t)f * (SPAN_N * KK * KK) + wrow);
#pragma unroll
      for (int c = 0; c < 7; ++c) {
        float4 wv = wf[c];                        // wave-uniform -> s_load_dwordx4
        acc[f] = fmaf(xv[c].x, wv.x, acc[f]);
        acc[f] = fmaf(xv[c].y, wv.y, acc[f]);
        acc[f] = fmaf(xv[c].z, wv.z, acc[f]);
        acc[f] = fmaf(xv[c].w, wv.w, acc[f]);
      }
    }
  }

  // reduce the 4 K-quarters across waves
  __shared__ float red[3][F_N * 64];
  if (kh > 0) {
#pragma unroll
    for (int f = 0; f < F_N; ++f) red[kh - 1][f * 64 + lane] = acc[f];
  }
  __syncthreads();
  if (kh == 0) {
#pragma unroll
    for (int f = 0; f < F_N; ++f) {
      float v = acc[f] + red[0][f * 64 + lane] + red[1][f * 64 + lane]
                       + red[2][f * 64 + lane];
      v += cb[f * SPAN_N + s];
      v = v > 0.f ? v : 0.f;
      hidden[(size_t)(f * SPAN_N + s) * B_TOT + b] = v;   // coalesced
    }
  }
}

// Kernel 2: y[b][o] = sum_d hidden[d][b] * dec_w[o][d] + dec_b[o]
// grid = 8 blocks x 512 threads (8 waves); wave wid handles d-range of 125;
// lane = b (coalesced hidden loads); dec_w loads wave-uniform (scalar).
__global__ __launch_bounds__(512) void lcn_dec(
    const float* __restrict__ hidden, const float* __restrict__ dw,
    const float* __restrict__ db, float* __restrict__ y) {
  const int bg   = blockIdx.x;          // 0..7
  const int wid  = threadIdx.x >> 6;    // 0..7
  const int lane = threadIdx.x & 63;
  const int b    = bg * 64 + lane;
  const int d0   = __builtin_amdgcn_readfirstlane(wid * (DEC_IN / 8));

  float acc[OUT_N];
#pragma unroll
  for (int o = 0; o < OUT_N; ++o) acc[o] = 0.f;

  for (int dd = 0; dd < DEC_IN / 8; ++dd) {
    const int d = d0 + dd;
    float h = hidden[(size_t)d * B_TOT + b];     // coalesced
#pragma unroll
    for (int o = 0; o < OUT_N; ++o)
      acc[o] = fmaf(h, dw[o * DEC_IN + d], acc[o]);  // wave-uniform -> s_load
  }

  __shared__ float red[7][OUT_N * 64];
  if (wid > 0) {
#pragma unroll
    for (int o = 0; o < OUT_N; ++o) red[wid - 1][o * 64 + lane] = acc[o];
  }
  __syncthreads();
  if (wid == 0) {
#pragma unroll
    for (int o = 0; o < OUT_N; ++o) {
      float v = acc[o];
#pragma unroll
      for (int k = 0; k < 7; ++k) v += red[k][o * 64 + lane];
      y[b * OUT_N + o] = v + db[o];
    }
  }
}

extern "C" void kernel_launch(void* const* d_in, const int* in_sizes, int n_in,
                              void* d_out, int out_size, void* d_ws, size_t ws_size,
                              hipStream_t stream) {
  const float* x  = (const float*)d_in[0];   // [512,1,280,280]
  const float* cw = (const float*)d_in[1];   // [1000,1,28,28]
  const float* cb = (const float*)d_in[2];   // [1000,1]
  const float* dw = (const float*)d_in[3];   // [10,1000]
  const float* db = (const float*)d_in[4];   // [10]
  float* y = (float*)d_out;                  // [512,10]

  // scratch: hidden [1000][512] fp32 = 2.048 MB in d_ws
  float* hidden = (float*)d_ws;

  lcn_conv<<<dim3(800), dim3(256), 0, stream>>>(x, cw, cb, hidden);
  lcn_dec<<<dim3(8), dim3(512), 0, stream>>>(hidden, dw, db, y);
}

// Round 2
// 79.157 us; speedup vs baseline: 1.6208x; 1.6208x over previous
//
#include <hip/hip_runtime.h>

// LCN: B=512, C=1, H=W=280, K=S=28, F=10, SPAN=100 (10x10), DEC_IN=1000, OUT=10
#define HW      280
#define B_TOT   512
#define KK      28
#define F_N     10
#define SPAN_N  100
#define OUT_N   10

// Fused locally-connected conv + bias + relu + per-s decoder partials.
// grid = 1600 blocks, XCD-swizzled decode: all 10 ws of a (bg,hs) land on one
// XCD so row line-straddles (shared between ws and ws+1) hit L2.
// block = 256 thr = 4 waves; wave covers 8 batches x 8 column-quads:
//   lane = (b_sub<<3) | c4 ; lanes c4=0..6 read the 28-float patch row as 7
//   contiguous float4 (112B segment per batch -> ~12 lines/instr vs 64 before).
// c4==7 lanes are inert in the conv (28 = 7*4) but help in the epilogue.
__global__ __launch_bounds__(256) void lcn_fused(
    const float* __restrict__ x, const float* __restrict__ cw,
    const float* __restrict__ cb, const float* __restrict__ dw,
    float* __restrict__ part) {
  const int bid   = blockIdx.x;
  const int xcd   = bid & 7;
  const int idx   = bid >> 3;             // 0..199
  const int ws    = idx % 10;
  const int combo = xcd * 20 + idx / 10;  // 0..159
  const int hs    = combo % 10;
  const int bg    = combo / 10;           // 0..15
  const int s     = hs * 10 + ws;

  const int lane = threadIdx.x & 63;
  const int wid  = threadIdx.x >> 6;
  const int c4   = lane & 7;              // column quad 0..7 (7 inert)
  const int b    = bg * 32 + wid * 8 + (lane >> 3);

  float acc[F_N];
#pragma unroll
  for (int f = 0; f < F_N; ++f) acc[f] = 0.f;

  if (c4 < 7) {
    const float* xp = x + (size_t)b * (HW * HW)
                        + (size_t)(hs * KK) * HW + ws * KK + c4 * 4;
    const float* wp = cw + s * (KK * KK) + c4 * 4;
#pragma unroll 4
    for (int r = 0; r < KK; ++r) {
      float4 xv = *reinterpret_cast<const float4*>(xp + (size_t)r * HW);
#pragma unroll
      for (int f = 0; f < F_N; ++f) {
        float4 wv = *reinterpret_cast<const float4*>(
            wp + (size_t)f * (SPAN_N * KK * KK) + r * KK);
        acc[f] = fmaf(xv.x, wv.x, acc[f]);
        acc[f] = fmaf(xv.y, wv.y, acc[f]);
        acc[f] = fmaf(xv.z, wv.z, acc[f]);
        acc[f] = fmaf(xv.w, wv.w, acc[f]);
      }
    }
  }

  // reduce the 784-sum across the 8-lane column group (c4==7 contributes 0)
#pragma unroll
  for (int f = 0; f < F_N; ++f) {
    acc[f] += __shfl_xor(acc[f], 1);
    acc[f] += __shfl_xor(acc[f], 2);
    acc[f] += __shfl_xor(acc[f], 4);
  }

  // all 8 lanes of a group now hold the full sums for their (shared) batch b
  float v[F_N];
#pragma unroll
  for (int f = 0; f < F_N; ++f) {
    float t = acc[f] + cb[f * SPAN_N + s];
    v[f] = t > 0.f ? t : 0.f;
  }

  // decoder partial for this s: p[o] = sum_f v[f] * dw[o][f*100+s]
  {
    const int o = c4;  // lanes 0..7 -> outputs 0..7
    float p = 0.f;
#pragma unroll
    for (int f = 0; f < F_N; ++f)
      p = fmaf(v[f], dw[o * (F_N * SPAN_N) + f * SPAN_N + s], p);
    part[((size_t)s * B_TOT + b) * OUT_N + o] = p;
  }
  if (c4 < 2) {
    const int o = 8 + c4;  // lanes 0,1 also do outputs 8,9
    float p = 0.f;
#pragma unroll
    for (int f = 0; f < F_N; ++f)
      p = fmaf(v[f], dw[o * (F_N * SPAN_N) + f * SPAN_N + s], p);
    part[((size_t)s * B_TOT + b) * OUT_N + o] = p;
  }
}

// y[b][o] = dec_b[o] + sum_s part[s][b][o]   (5120 outputs, 20 blocks)
__global__ __launch_bounds__(256) void lcn_reduce(
    const float* __restrict__ part, const float* __restrict__ db,
    float* __restrict__ y) {
  const int idx = blockIdx.x * 256 + threadIdx.x;  // 0..5119
  const int o   = idx % OUT_N;
  float acc = db[o];
  for (int s = 0; s < SPAN_N; ++s)
    acc += part[(size_t)s * (B_TOT * OUT_N) + idx];  // coalesced per s
  y[idx] = acc;
}

extern "C" void kernel_launch(void* const* d_in, const int* in_sizes, int n_in,
                              void* d_out, int out_size, void* d_ws, size_t ws_size,
                              hipStream_t stream) {
  const float* x  = (const float*)d_in[0];   // [512,1,280,280]
  const float* cw = (const float*)d_in[1];   // [1000,1,28,28]
  const float* cb = (const float*)d_in[2];   // [1000,1]
  const float* dw = (const float*)d_in[3];   // [10,1000]
  const float* db = (const float*)d_in[4];   // [10]
  float* y = (float*)d_out;                  // [512,10]

  // scratch: part [100][512][10] fp32 = 2.048 MB
  float* part = (float*)d_ws;

  lcn_fused<<<dim3(1600), dim3(256), 0, stream>>>(x, cw, cb, dw, part);
  lcn_reduce<<<dim3(20), dim3(256), 0, stream>>>(part, db, y);
}

// Round 3
// 52.856 us; speedup vs baseline: 2.4273x; 1.4976x over previous
//
#include <hip/hip_runtime.h>

// LCN: B=512, C=1, H=W=280, K=S=28, F=10, SPAN=100 (10x10), DEC_IN=1000, OUT=10
#define HW      280
#define B_TOT   512
#define KK      28
#define F_N     10
#define SPAN_N  100
#define OUT_N   10

// Fused locally-connected conv + bias + relu + per-s decoder partials.
// grid = 1600 blocks (XCD-swizzled); block = 256 thr = 4 waves.
// Wave layout: lane = (b_sub<<3)|c4 ; 8 batches x 8 column-quads; c4==7 inert
// in the conv (28 = 7*4), active in the epilogue.
// NEW vs round 2: w slice for this block's s (10 f x 784 = 31.4 KB) is staged
// in LDS once -> hot loop reads w via ds_read_b128 (7 distinct addrs x 112 B,
// broadcast across the 8 batch groups, conflict-free) instead of 10 per-lane
// VMEM loads that thrashed L1 against the x stream (latency-bound, 15% VALU).
__global__ __launch_bounds__(256) void lcn_fused(
    const float* __restrict__ x, const float* __restrict__ cw,
    const float* __restrict__ cb, const float* __restrict__ dw,
    float* __restrict__ part) {
  const int bid   = blockIdx.x;
  const int xcd   = bid & 7;
  const int idx   = bid >> 3;             // 0..199
  const int ws    = idx % 10;
  const int combo = xcd * 20 + idx / 10;  // 0..159
  const int hs    = combo % 10;
  const int bg    = combo / 10;           // 0..15
  const int s     = hs * 10 + ws;

  const int lane = threadIdx.x & 63;
  const int wid  = threadIdx.x >> 6;
  const int c4   = lane & 7;              // column quad 0..7 (7 inert in conv)
  const int b    = bg * 32 + wid * 8 + (lane >> 3);

  // stage w[f][k] for this s: 10*784 floats = 1960 float4 = 31.36 KB
  __shared__ float wlds[F_N * KK * KK];
  {
    float4*       wl = reinterpret_cast<float4*>(wlds);
    const float4* wg = reinterpret_cast<const float4*>(cw);
    for (int i = threadIdx.x; i < F_N * 196; i += 256) {
      const int f = i / 196, q = i - f * 196;
      wl[i] = wg[(f * SPAN_N + s) * 196 + q];   // [f][q] <- cw[f*100+s][q]
    }
  }
  __syncthreads();

  float acc[F_N];
#pragma unroll
  for (int f = 0; f < F_N; ++f) acc[f] = 0.f;

  if (c4 < 7) {
    const float*  xp = x + (size_t)b * (HW * HW)
                         + (size_t)(hs * KK) * HW + ws * KK + c4 * 4;
    const float4* wl = reinterpret_cast<const float4*>(wlds);
#pragma unroll 7
    for (int r = 0; r < KK; ++r) {
      float4 xv = *reinterpret_cast<const float4*>(xp + (size_t)r * HW);
#pragma unroll
      for (int f = 0; f < F_N; ++f) {
        float4 wv = wl[f * 196 + r * 7 + c4];   // ds_read_b128, broadcast x8
        acc[f] = fmaf(xv.x, wv.x, acc[f]);
        acc[f] = fmaf(xv.y, wv.y, acc[f]);
        acc[f] = fmaf(xv.z, wv.z, acc[f]);
        acc[f] = fmaf(xv.w, wv.w, acc[f]);
      }
    }
  }

  // reduce the 784-sum across the 8-lane column group (c4==7 contributes 0)
#pragma unroll
  for (int f = 0; f < F_N; ++f) {
    acc[f] += __shfl_xor(acc[f], 1);
    acc[f] += __shfl_xor(acc[f], 2);
    acc[f] += __shfl_xor(acc[f], 4);
  }

  // all 8 lanes of a group now hold the full sums for their batch b
  float v[F_N];
#pragma unroll
  for (int f = 0; f < F_N; ++f) {
    float t = acc[f] + cb[f * SPAN_N + s];
    v[f] = t > 0.f ? t : 0.f;
  }

  // decoder partial for this s: p[o] = sum_f v[f] * dw[o][f*100+s]
  {
    const int o = c4;  // lanes 0..7 -> outputs 0..7
    float p = 0.f;
#pragma unroll
    for (int f = 0; f < F_N; ++f)
      p = fmaf(v[f], dw[o * (F_N * SPAN_N) + f * SPAN_N + s], p);
    part[((size_t)s * B_TOT + b) * OUT_N + o] = p;
  }
  if (c4 < 2) {
    const int o = 8 + c4;  // lanes 0,1 also do outputs 8,9
    float p = 0.f;
#pragma unroll
    for (int f = 0; f < F_N; ++f)
      p = fmaf(v[f], dw[o * (F_N * SPAN_N) + f * SPAN_N + s], p);
    part[((size_t)s * B_TOT + b) * OUT_N + o] = p;
  }
}

// y[b][o] = dec_b[o] + sum_s part[s][b][o]   (5120 outputs, 20 blocks)
__global__ __launch_bounds__(256) void lcn_reduce(
    const float* __restrict__ part, const float* __restrict__ db,
    float* __restrict__ y) {
  const int idx = blockIdx.x * 256 + threadIdx.x;  // 0..5119
  const int o   = idx % OUT_N;
  float acc = db[o];
  for (int s = 0; s < SPAN_N; ++s)
    acc += part[(size_t)s * (B_TOT * OUT_N) + idx];  // coalesced per s
  y[idx] = acc;
}

extern "C" void kernel_launch(void* const* d_in, const int* in_sizes, int n_in,
                              void* d_out, int out_size, void* d_ws, size_t ws_size,
                              hipStream_t stream) {
  const float* x  = (const float*)d_in[0];   // [512,1,280,280]
  const float* cw = (const float*)d_in[1];   // [1000,1,28,28]
  const float* cb = (const float*)d_in[2];   // [1000,1]
  const float* dw = (const float*)d_in[3];   // [10,1000]
  const float* db = (const float*)d_in[4];   // [10]
  float* y = (float*)d_out;                  // [512,10]

  // scratch: part [100][512][10] fp32 = 2.048 MB
  float* part = (float*)d_ws;

  lcn_fused<<<dim3(1600), dim3(256), 0, stream>>>(x, cw, cb, dw, part);
  lcn_reduce<<<dim3(20), dim3(256), 0, stream>>>(part, db, y);
}